// Round 2
// baseline (397.784 us; speedup 1.0000x reference)
//
#include <hip/hip_runtime.h>

// x = (32, 256, 56, 56) fp32; 16 groups of 16 channels
#define M_BATCH 32
#define D_FEAT 256
#define HW 3136
#define NGROUPS 16
#define GS 16
#define NTOT (M_BATCH * HW)
#define TRI 136
#define EPS_W 1e-6f

__device__ __host__ constexpr int tidx(int i, int j) { return i * (i + 1) / 2 + j; }

// ---------------------------------------------------------------------------
// Pass 1: quarter-split Gram. lane = (q = lane>>4 owns channels 4q..4q+3,
// c = lane&15 indexes columns). Thread accumulates own-chunk triangle (10)
// plus own x lower-chunk 4x4 blocks (48, computed unconditionally; cells with
// qp >= q are valid numbers but simply never written out).
// ---------------------------------------------------------------------------
#define ST_SLICES 2
#define ST_COLS (HW / ST_SLICES)        // 1568 (divisible by 16)
#define ST_ITERS ((ST_COLS + 63) / 64)  // 25 (last iter: waves 0,1 only)

__global__ __launch_bounds__(256, 4) void whiten_stats(const float* __restrict__ x,
                                                       float* __restrict__ sums,
                                                       float* __restrict__ gram) {
    const int b = blockIdx.x, g = blockIdx.y, sl = blockIdx.z;
    const int wv = threadIdx.x >> 6;
    const int l  = threadIdx.x & 63;
    const int q  = l >> 4;
    const int c  = l & 15;
    const float* base = x + ((size_t)b * D_FEAT + (size_t)g * GS) * HW + (size_t)sl * ST_COLS;

    float s[4] = {0.f, 0.f, 0.f, 0.f};
    float accT[10];
    float accX[3][4][4];
#pragma unroll
    for (int t = 0; t < 10; ++t) accT[t] = 0.f;
#pragma unroll
    for (int qp = 0; qp < 3; ++qp)
#pragma unroll
        for (int a = 0; a < 4; ++a)
#pragma unroll
            for (int d = 0; d < 4; ++d) accX[qp][a][d] = 0.f;

    for (int k = 0; k < ST_ITERS; ++k) {
        const int p = k * 64 + wv * 16 + c;
        // guard is wave-uniform (ST_COLS % 16 == 0, p independent of q)
        if (p < ST_COLS) {
            float v[4];
#pragma unroll
            for (int j = 0; j < 4; ++j) v[j] = base[(size_t)(4 * q + j) * HW + p];
#pragma unroll
            for (int j = 0; j < 4; ++j) s[j] += v[j];
            float rc[3][4];
#pragma unroll
            for (int qp = 0; qp < 3; ++qp)
#pragma unroll
                for (int j = 0; j < 4; ++j)
                    rc[qp][j] = __shfl(v[j], qp * 16 + c, 64);
            // own-chunk triangle
#pragma unroll
            for (int a = 0; a < 4; ++a)
#pragma unroll
                for (int d = 0; d <= a; ++d)
                    accT[tidx(a, d)] = fmaf(v[a], v[d], accT[tidx(a, d)]);
            // own x chunk-qp blocks (unconditional; only qp<q written later)
#pragma unroll
            for (int qp = 0; qp < 3; ++qp)
#pragma unroll
                for (int a = 0; a < 4; ++a)
#pragma unroll
                    for (int d = 0; d < 4; ++d)
                        accX[qp][a][d] = fmaf(v[a], rc[qp][d], accX[qp][a][d]);
        }
    }

    // reduce across the 16 column-lanes (xor on bits 0..3 preserves q)
#pragma unroll
    for (int m = 1; m <= 8; m <<= 1) {
#pragma unroll
        for (int j = 0; j < 4; ++j) s[j] += __shfl_xor(s[j], m, 64);
#pragma unroll
        for (int t = 0; t < 10; ++t) accT[t] += __shfl_xor(accT[t], m, 64);
#pragma unroll
        for (int qp = 0; qp < 3; ++qp)
#pragma unroll
            for (int a = 0; a < 4; ++a)
#pragma unroll
                for (int d = 0; d < 4; ++d)
                    accX[qp][a][d] += __shfl_xor(accX[qp][a][d], m, 64);
    }

    if (c == 0) {
#pragma unroll
        for (int j = 0; j < 4; ++j) atomicAdd(&sums[g * GS + 4 * q + j], s[j]);
#pragma unroll
        for (int a = 0; a < 4; ++a)
#pragma unroll
            for (int d = 0; d <= a; ++d)
                atomicAdd(&gram[g * TRI + tidx(4 * q + a, 4 * q + d)], accT[tidx(a, d)]);
#pragma unroll
        for (int qp = 0; qp < 3; ++qp) {
            if (qp < q) {
#pragma unroll
                for (int a = 0; a < 4; ++a)
#pragma unroll
                    for (int d = 0; d < 4; ++d)
                        atomicAdd(&gram[g * TRI + tidx(4 * q + a, 4 * qp + d)], accX[qp][a][d]);
            }
        }
    }
}

// ---------------------------------------------------------------------------
// Pass 2: sigma -> Cholesky -> inv(T) -> zero-padded W (16x16) + bias = -W mu.
// 16 groups in 16 lanes of one wave; no launch_bounds so VGPRs are unlimited
// (needs ~180 regs, 1 wave only).
// ---------------------------------------------------------------------------
__global__ void whiten_solve(const float* __restrict__ sums,
                             const float* __restrict__ gram,
                             float* __restrict__ wfull,
                             float* __restrict__ bias) {
    const int g = threadIdx.x;
    if (g >= NGROUPS) return;

    float mu[GS];
#pragma unroll
    for (int j = 0; j < GS; ++j) mu[j] = sums[g * GS + j] * (1.0f / (float)NTOT);

    float S[TRI];
#pragma unroll
    for (int i = 0; i < GS; ++i) {
#pragma unroll
        for (int j = 0; j <= i; ++j) {
            float sg = (gram[g * TRI + tidx(i, j)] - (float)NTOT * mu[i] * mu[j])
                       * (1.0f / (float)(NTOT - 1));
            sg *= (1.0f - EPS_W);
            if (i == j) sg += EPS_W;
            S[tidx(i, j)] = sg;
        }
    }

    // In-place Cholesky: S becomes T (lower).
#pragma unroll
    for (int cc = 0; cc < GS; ++cc) {
        float d = S[tidx(cc, cc)];
#pragma unroll
        for (int k = 0; k < cc; ++k) d -= S[tidx(cc, k)] * S[tidx(cc, k)];
        d = sqrtf(d);
        S[tidx(cc, cc)] = d;
        const float inv = 1.0f / d;
#pragma unroll
        for (int i = cc + 1; i < GS; ++i) {
            float t = S[tidx(i, cc)];
#pragma unroll
            for (int k = 0; k < cc; ++k) t -= S[tidx(i, k)] * S[tidx(cc, k)];
            S[tidx(i, cc)] = t * inv;
        }
    }

    // In-place inverse of lower-triangular T: S becomes W = T^{-1}.
#pragma unroll
    for (int cc = 0; cc < GS; ++cc) {
        const float wcc = 1.0f / S[tidx(cc, cc)];
        S[tidx(cc, cc)] = wcc;
#pragma unroll
        for (int i = cc + 1; i < GS; ++i) {
            float a = 0.0f;
#pragma unroll
            for (int k = cc; k < i; ++k) a += S[tidx(i, k)] * S[tidx(k, cc)];
            S[tidx(i, cc)] = -a / S[tidx(i, i)];
        }
    }

#pragma unroll
    for (int i = 0; i < GS; ++i) {
        float acc = 0.f;
#pragma unroll
        for (int j = 0; j <= i; ++j) acc += S[tidx(i, j)] * mu[j];
        bias[g * GS + i] = -acc;
#pragma unroll
        for (int j = 0; j < GS; ++j)
            wfull[g * 256 + i * 16 + j] = (j <= i) ? S[tidx(i, j)] : 0.f;
    }
}

// ---------------------------------------------------------------------------
// Pass 3: out = W x + bias. Quarter-split: each thread computes 4 output rows
// (zero-padded W rows = 64 regs), gathers all 16 inputs of its column via
// 16 shuffles.
// ---------------------------------------------------------------------------
#define AP_SLICES 7
#define AP_COLS (HW / AP_SLICES)  // 448
#define AP_ITERS (AP_COLS / 64)   // 7, exact

__global__ __launch_bounds__(256, 4) void whiten_apply(const float* __restrict__ x,
                                                       const float* __restrict__ wfull,
                                                       const float* __restrict__ bias,
                                                       float* __restrict__ out) {
    const int b = blockIdx.x, g = blockIdx.y, sl = blockIdx.z;
    const int wv = threadIdx.x >> 6;
    const int l  = threadIdx.x & 63;
    const int q  = l >> 4;
    const int c  = l & 15;
    const size_t off0 = ((size_t)b * D_FEAT + (size_t)g * GS) * HW + (size_t)sl * AP_COLS;
    const float* base = x + off0;
    float* obase = out + off0;

    float wrow[4][16];
    const float* wg = wfull + g * 256;
#pragma unroll
    for (int a = 0; a < 4; ++a) {
        const float4* wr = (const float4*)(wg + (4 * q + a) * 16);
#pragma unroll
        for (int j4 = 0; j4 < 4; ++j4) {
            float4 t = wr[j4];
            wrow[a][4 * j4 + 0] = t.x;
            wrow[a][4 * j4 + 1] = t.y;
            wrow[a][4 * j4 + 2] = t.z;
            wrow[a][4 * j4 + 3] = t.w;
        }
    }
    float brow[4];
#pragma unroll
    for (int a = 0; a < 4; ++a) brow[a] = bias[g * GS + 4 * q + a];

    for (int k = 0; k < AP_ITERS; ++k) {
        const int p = k * 64 + wv * 16 + c;
        float v[4];
#pragma unroll
        for (int j = 0; j < 4; ++j) v[j] = base[(size_t)(4 * q + j) * HW + p];
        float vall[16];
#pragma unroll
        for (int m = 0; m < 16; ++m)
            vall[m] = __shfl(v[m & 3], (m >> 2) * 16 + c, 64);
        float acc[4];
#pragma unroll
        for (int a = 0; a < 4; ++a) acc[a] = brow[a];
#pragma unroll
        for (int a = 0; a < 4; ++a)
#pragma unroll
            for (int j = 0; j < 16; ++j)
                acc[a] = fmaf(wrow[a][j], vall[j], acc[a]);
#pragma unroll
        for (int a = 0; a < 4; ++a)
            obase[(size_t)(4 * q + a) * HW + p] = acc[a];
    }
}

extern "C" void kernel_launch(void* const* d_in, const int* in_sizes, int n_in,
                              void* d_out, int out_size, void* d_ws, size_t ws_size,
                              hipStream_t stream) {
    const float* x = (const float*)d_in[0];
    float* out = (float*)d_out;

    float* ws    = (float*)d_ws;
    float* sums  = ws;          // 256
    float* gram  = ws + 256;    // 2176
    float* wfull = ws + 2432;   // 4096 (16 groups x 16x16, zero-padded)
    float* bias  = ws + 6528;   // 256

    hipMemsetAsync(ws, 0, 2432 * sizeof(float), stream);

    whiten_stats<<<dim3(M_BATCH, NGROUPS, ST_SLICES), 256, 0, stream>>>(x, sums, gram);
    whiten_solve<<<1, 64, 0, stream>>>(sums, gram, wfull, bias);
    whiten_apply<<<dim3(M_BATCH, NGROUPS, AP_SLICES), 256, 0, stream>>>(x, wfull, bias, out);
}